// Round 2
// baseline (4955.634 us; speedup 1.0000x reference)
//
#include <hip/hip_runtime.h>

// ws layout (floats)
#define WS_GX   0                       // 4096: Gx[cp][c] = alpha*sum_o wk[o][c]*wq[o][cp]
#define WS_CPV  4096                    // 4096: Cpvx[c][o] = sum_m wp[o][m]*wv[m][c]
#define WS_QB   8192                    // 64:   alpha * Wk^T bq
#define WS_BPV  8256                    // 64:   Wp bv + bp
#define WS_C2   8448                    // 4096*1536 conv2 output (flattened fc input)
#define WS_Z1   (8448 + 4096*1536)      // 4096*768 fc1 output

// ---------------- K0: tiny precompute of fused weight products ----------------
__global__ void k0_precompute(const float* __restrict__ wq, const float* __restrict__ bq,
                              const float* __restrict__ wk, const float* __restrict__ bk,
                              const float* __restrict__ wv, const float* __restrict__ bv,
                              const float* __restrict__ wp, const float* __restrict__ bp,
                              float* __restrict__ ws) {
  int idx = blockIdx.x * 256 + threadIdx.x;
  const float ALPHA = 0.125f * 1.4426950408889634f;  // C^-0.5 * log2(e), folded into scores
  if (idx < 4096) {
    int cp = idx >> 6, c = idx & 63;
    float s = 0.f;
    for (int o = 0; o < 64; ++o) s += wk[o*64 + c] * wq[o*64 + cp];
    ws[WS_GX + idx] = s * ALPHA;
  } else if (idx < 8192) {
    int i = idx - 4096; int c = i >> 6, o = i & 63;
    float s = 0.f;
    for (int m = 0; m < 64; ++m) s += wp[o*64 + m] * wv[m*64 + c];
    ws[WS_CPV + i] = s;
  } else if (idx < 8256) {
    int c = idx - 8192;
    float s = 0.f;
    for (int o = 0; o < 64; ++o) s += wk[o*64 + c] * bq[o];
    ws[WS_QB + c] = s * ALPHA;
  } else if (idx < 8320) {
    int o = idx - 8256;
    float s = bp[o];
    for (int m = 0; m < 64; ++m) s += wp[o*64 + m] * bv[m];
    ws[WS_BPV + o] = s;
  }
}

// ---------------- K1: per-sample pipeline (conv1 -> GN -> attention -> conv2) ----------------
// block = 384 threads = 2 threads per token (t = tid>>1, half = tid&1).
// Each thread owns 32 of the 64 channels -> qt[32]/gacc[32] fit in VGPRs (no spill).
// Pair lanes (2t, 2t+1) are wave-adjacent: full 64-ch score dot = partial + __shfl_xor(.,1).
// Hs layout: channel-major [c][196] (16B-aligned rows for broadcast ds_read_b128).
__launch_bounds__(384, 2)
__global__ void k1_sample(const float* __restrict__ x,
                          const float* __restrict__ w1, const float* __restrict__ b1,
                          const float* __restrict__ chw, const float* __restrict__ chb,
                          const float* __restrict__ gnw, const float* __restrict__ gnb,
                          const float* __restrict__ ch2w, const float* __restrict__ ch2b,
                          const float* __restrict__ ws, float* __restrict__ c2out) {
  __shared__ float Hs[64 * 196];
  __shared__ float redS[384];
  __shared__ float redQ[384];
  __shared__ float scS[64];
  __shared__ float shS[64];

  const int tid  = threadIdx.x;
  const int t    = tid >> 1;        // token 0..191
  const int half = tid & 1;         // channel half
  const int c0   = half * 32;       // my channel base
  const int b    = blockIdx.x;      // sample
  const int y    = t >> 6;          // 0..2
  const int xx   = t & 63;          // 0..63

  const float x0 = x[b*3+0], x1 = x[b*3+1], x2 = x[b*3+2];

  // h1 window values hv[dy*3+dx] = h1[y+dy-1][xx+dx-1] with zero padding.
  float hv[9];
  {
    #pragma unroll
    for (int dy = 0; dy < 3; ++dy) {
      int r = y + dy - 1;
      bool rv = (r >= 0) && (r < 3);
      float xr = (r == 0) ? x0 : ((r == 1) ? x1 : x2);
      #pragma unroll
      for (int dx = 0; dx < 3; ++dx) {
        int cc = xx + dx - 1;
        bool cv = (cc >= 0) && (cc < 64);
        float w1v = cv ? w1[cc] : 0.f;
        float b1v = cv ? b1[cc] : 0.f;
        hv[dy*3+dx] = rv ? fmaf(xr, w1v, cv ? b1v : 0.f) : 0.f;
      }
    }
  }

  // conv1 (1->64): thread writes its 32 channels at token t
  for (int j = 0; j < 32; ++j) {
    int c = c0 + j;
    float acc = chb[c];
    #pragma unroll
    for (int q = 0; q < 9; ++q) acc = fmaf(chw[c*9+q], hv[q], acc);
    Hs[c*196 + t] = acc;
  }
  __syncthreads();

  // instance-norm stats: thread tid handles channel c=tid&63, segment seg=tid>>6 (6 segs x 32 tokens)
  {
    int c = tid & 63, seg = tid >> 6;
    float s = 0.f, q = 0.f;
    int base = c*196 + seg*32;
    for (int u = 0; u < 32; ++u) { float v = Hs[base + u]; s += v; q = fmaf(v, v, q); }
    redS[tid] = s; redQ[tid] = q;
  }
  __syncthreads();
  if (tid < 64) {
    float s = 0.f, q = 0.f;
    #pragma unroll
    for (int g = 0; g < 6; ++g) { s += redS[g*64 + tid]; q += redQ[g*64 + tid]; }
    float mu  = s * (1.f/192.f);
    float var = q * (1.f/192.f) - mu*mu;
    float rs  = rsqrtf(var + 1e-5f);
    float sc  = gnw[tid] * rs;
    scS[tid] = sc;
    shS[tid] = gnb[tid] - mu * sc;
  }
  __syncthreads();
  // normalize in place (my 32 channels at token t)
  for (int j = 0; j < 32; ++j) {
    int c = c0 + j;
    Hs[c*196 + t] = fmaf(Hs[c*196 + t], scS[c], shS[c]);
  }
  __syncthreads();

  // ---- attention ----
  const float* __restrict__ Gx  = ws + WS_GX;
  const float* __restrict__ qb  = ws + WS_QB;
  const float* __restrict__ Cpv = ws + WS_CPV;
  const float* __restrict__ bpv = ws + WS_BPV;

  // q~[c] for my 32 channels: qt[j] = qb[c0+j] + sum_cp Gx[cp][c0+j]*h[cp][t]
  float qt[32];
  #pragma unroll
  for (int j = 0; j < 32; ++j) qt[j] = qb[c0 + j];
  for (int cp = 0; cp < 64; ++cp) {
    float h = Hs[cp*196 + t];
    const float* g = Gx + cp*64 + c0;
    #pragma unroll
    for (int j = 0; j < 32; ++j) qt[j] = fmaf(g[j], h, qt[j]);
  }

  // online softmax + g = attn @ h  (partial scores over 32 ch, pair-combined via shfl_xor)
  float gacc[32];
  #pragma unroll
  for (int j = 0; j < 32; ++j) gacc[j] = 0.f;
  float m = -1e30f, l = 0.f;
  for (int u0 = 0; u0 < 192; u0 += 4) {
    float s0 = 0.f, s1 = 0.f, s2 = 0.f, s3 = 0.f;
    #pragma unroll
    for (int j = 0; j < 32; ++j) {
      const float4 h4 = *(const float4*)&Hs[(c0+j)*196 + u0];
      float q = qt[j];
      s0 = fmaf(q, h4.x, s0); s1 = fmaf(q, h4.y, s1);
      s2 = fmaf(q, h4.z, s2); s3 = fmaf(q, h4.w, s3);
    }
    // complete the 64-ch dot with the pair lane
    s0 += __shfl_xor(s0, 1); s1 += __shfl_xor(s1, 1);
    s2 += __shfl_xor(s2, 1); s3 += __shfl_xor(s3, 1);

    float mn = fmaxf(fmaxf(fmaxf(s0, s1), fmaxf(s2, s3)), m);
    float alpha = __builtin_exp2f(m - mn);
    float p0 = __builtin_exp2f(s0 - mn);
    float p1 = __builtin_exp2f(s1 - mn);
    float p2 = __builtin_exp2f(s2 - mn);
    float p3 = __builtin_exp2f(s3 - mn);
    l = fmaf(l, alpha, (p0 + p1) + (p2 + p3));
    m = mn;
    #pragma unroll
    for (int j = 0; j < 32; ++j) {
      const float4 h4 = *(const float4*)&Hs[(c0+j)*196 + u0];
      float gg = gacc[j] * alpha;
      gg = fmaf(p0, h4.x, gg); gg = fmaf(p1, h4.y, gg);
      gg = fmaf(p2, h4.z, gg); gg = fmaf(p3, h4.w, gg);
      gacc[j] = gg;
    }
  }
  {
    float rl = 1.f / l;
    #pragma unroll
    for (int j = 0; j < 32; ++j) gacc[j] *= rl;
  }

  // p[o] = bpv[o] + sum_c Cpv[c][o]*g[c], computed in two 32-o chunks, pair-combined.
  // Thread keeps the chunk matching its channel half (residual add target).
  float keep[32];
  #pragma unroll
  for (int o = 0; o < 32; ++o) keep[o] = 0.f;
  #pragma unroll
  for (int chunk = 0; chunk < 2; ++chunk) {
    float part[32];
    #pragma unroll
    for (int o = 0; o < 32; ++o) part[o] = 0.f;
    for (int j = 0; j < 32; ++j) {
      float g = gacc[j];
      const float* cp = Cpv + (c0 + j)*64 + chunk*32;
      #pragma unroll
      for (int o = 0; o < 32; ++o) part[o] = fmaf(cp[o], g, part[o]);
    }
    #pragma unroll
    for (int o = 0; o < 32; ++o) {
      float comb = part[o] + __shfl_xor(part[o], 1);
      keep[o] = (half == chunk) ? comb : keep[o];
    }
  }
  #pragma unroll
  for (int o = 0; o < 32; ++o) keep[o] += bpv[c0 + o];

  __syncthreads();   // all attention reads of Hs complete before overwrite

  // residual: res[c][t] = conv1(c,t) (recomputed from hv) + p[c]
  for (int j = 0; j < 32; ++j) {
    int c = c0 + j;
    float acc = chb[c];
    #pragma unroll
    for (int q = 0; q < 9; ++q) acc = fmaf(chw[c*9+q], hv[q], acc);
    Hs[c*196 + t] = acc + keep[j];
  }
  __syncthreads();

  // conv2 (64->8): thread computes 4 outputs (oc = half*4 .. half*4+3) at token t
  float acc2[4];
  #pragma unroll
  for (int o = 0; o < 4; ++o) acc2[o] = ch2b[half*4 + o];
  for (int c = 0; c < 64; ++c) {
    float win[9];
    #pragma unroll
    for (int dy = 0; dy < 3; ++dy) {
      int r = y + dy - 1;
      bool rv = (r >= 0) && (r < 3);
      #pragma unroll
      for (int dx = 0; dx < 3; ++dx) {
        int cc = xx + dx - 1;
        bool cv = (cc >= 0) && (cc < 64);
        win[dy*3+dx] = (rv && cv) ? Hs[c*196 + r*64 + cc] : 0.f;
      }
    }
    #pragma unroll
    for (int o = 0; o < 4; ++o) {
      const float* w = ch2w + (half*4 + o)*576 + c*9;
      float a = acc2[o];
      #pragma unroll
      for (int q = 0; q < 9; ++q) a = fmaf(w[q], win[q], a);
      acc2[o] = a;
    }
  }
  #pragma unroll
  for (int o = 0; o < 4; ++o) c2out[b*1536 + (half*4 + o)*192 + t] = acc2[o];
}

// ---------------- K2: fc1 GEMM  z1[4096][768] = relu(c2[4096][1536] @ w2^T + b2) ----------------
__launch_bounds__(256, 4)
__global__ void k2_fc1(const float* __restrict__ A, const float* __restrict__ w2,
                       const float* __restrict__ b2, float* __restrict__ z1) {
  __shared__ float As[128 * 33];
  __shared__ float Bs[32 * 68];
  const int tid = threadIdx.x;
  const int m0 = blockIdx.x * 128;
  const int n0 = blockIdx.y * 64;
  const int tm = tid & 15, tn = tid >> 4;   // tn 0..15

  float acc[8][4];
  #pragma unroll
  for (int i = 0; i < 8; ++i)
    #pragma unroll
    for (int j = 0; j < 4; ++j) acc[i][j] = 0.f;

  for (int k0 = 0; k0 < 1536; k0 += 32) {
    #pragma unroll
    for (int i = 0; i < 4; ++i) {   // stage A 128x32
      int j = tid + i*256;
      int mm = j >> 3, k4 = (j & 7) << 2;
      float4 v = *(const float4*)&A[(m0+mm)*1536 + k0 + k4];
      As[mm*33 + k4+0] = v.x; As[mm*33 + k4+1] = v.y;
      As[mm*33 + k4+2] = v.z; As[mm*33 + k4+3] = v.w;
    }
    #pragma unroll
    for (int i = 0; i < 2; ++i) {   // stage B 64x32 transposed -> Bs[k][68]
      int j = tid + i*256;
      int nn = j >> 3, k4 = (j & 7) << 2;
      float4 v = *(const float4*)&w2[(n0+nn)*1536 + k0 + k4];
      Bs[(k4+0)*68 + nn] = v.x; Bs[(k4+1)*68 + nn] = v.y;
      Bs[(k4+2)*68 + nn] = v.z; Bs[(k4+3)*68 + nn] = v.w;
    }
    __syncthreads();
    #pragma unroll
    for (int k = 0; k < 32; ++k) {
      float a[8];
      #pragma unroll
      for (int i = 0; i < 8; ++i) a[i] = As[(tm + 16*i)*33 + k];
      float4 bv = *(const float4*)&Bs[k*68 + tn*4];
      #pragma unroll
      for (int i = 0; i < 8; ++i) {
        acc[i][0] = fmaf(a[i], bv.x, acc[i][0]);
        acc[i][1] = fmaf(a[i], bv.y, acc[i][1]);
        acc[i][2] = fmaf(a[i], bv.z, acc[i][2]);
        acc[i][3] = fmaf(a[i], bv.w, acc[i][3]);
      }
    }
    __syncthreads();
  }
  float4 bb = *(const float4*)&b2[n0 + tn*4];
  #pragma unroll
  for (int i = 0; i < 8; ++i) {
    float4 r;
    r.x = fmaxf(acc[i][0] + bb.x, 0.f);
    r.y = fmaxf(acc[i][1] + bb.y, 0.f);
    r.z = fmaxf(acc[i][2] + bb.z, 0.f);
    r.w = fmaxf(acc[i][3] + bb.w, 0.f);
    *(float4*)&z1[(m0 + tm + 16*i)*768 + n0 + tn*4] = r;
  }
}

// ---------------- K3: fc2+relu+fc3  out[b] = b4 + sum_o w4[o]*relu(b3[o] + w3[o].z1[b]) ----------------
__launch_bounds__(256, 2)
__global__ void k3_fc23(const float* __restrict__ z1, const float* __restrict__ w3,
                        const float* __restrict__ b3, const float* __restrict__ w4,
                        const float* __restrict__ b4, float* __restrict__ out) {
  __shared__ float Zs[16 * 772];
  __shared__ float Ws[32 * 68];
  __shared__ float red[256];
  const int tid = threadIdx.x;
  const int m0 = blockIdx.x * 16;
  const int tm = tid & 15, tn = tid >> 4;   // tn 0..15 -> 4 fc2 outputs each

  #pragma unroll
  for (int i = 0; i < 12; ++i) {   // stage Zs 16x768
    int j = tid + i*256;
    int mm = j / 192;
    int kq = j - mm*192;
    float4 v = *(const float4*)&z1[(m0+mm)*768 + kq*4];
    *(float4*)&Zs[mm*772 + kq*4] = v;
  }

  float a0 = 0.f, a1 = 0.f, a2 = 0.f, a3 = 0.f;
  for (int k0 = 0; k0 < 768; k0 += 32) {
    __syncthreads();
    #pragma unroll
    for (int i = 0; i < 2; ++i) {  // stage Ws[32k][68] transposed from w3[n][k]
      int j = tid + i*256;
      int nn = j >> 3, k4 = (j & 7) << 2;
      float4 v = *(const float4*)&w3[nn*768 + k0 + k4];
      Ws[(k4+0)*68 + nn] = v.x; Ws[(k4+1)*68 + nn] = v.y;
      Ws[(k4+2)*68 + nn] = v.z; Ws[(k4+3)*68 + nn] = v.w;
    }
    __syncthreads();
    #pragma unroll
    for (int k = 0; k < 32; k += 4) {
      float4 z  = *(const float4*)&Zs[tm*772 + k0 + k];
      float4 w0 = *(const float4*)&Ws[(k+0)*68 + tn*4];
      float4 w1v= *(const float4*)&Ws[(k+1)*68 + tn*4];
      float4 w2v= *(const float4*)&Ws[(k+2)*68 + tn*4];
      float4 w3v= *(const float4*)&Ws[(k+3)*68 + tn*4];
      a0 = fmaf(z.x, w0.x, a0); a1 = fmaf(z.x, w0.y, a1); a2 = fmaf(z.x, w0.z, a2); a3 = fmaf(z.x, w0.w, a3);
      a0 = fmaf(z.y, w1v.x, a0); a1 = fmaf(z.y, w1v.y, a1); a2 = fmaf(z.y, w1v.z, a2); a3 = fmaf(z.y, w1v.w, a3);
      a0 = fmaf(z.z, w2v.x, a0); a1 = fmaf(z.z, w2v.y, a1); a2 = fmaf(z.z, w2v.z, a2); a3 = fmaf(z.z, w2v.w, a3);
      a0 = fmaf(z.w, w3v.x, a0); a1 = fmaf(z.w, w3v.y, a1); a2 = fmaf(z.w, w3v.z, a2); a3 = fmaf(z.w, w3v.w, a3);
    }
  }
  float4 b3v = *(const float4*)&b3[tn*4];
  float4 w4v = *(const float4*)&w4[tn*4];
  float p = fmaxf(a0 + b3v.x, 0.f) * w4v.x
          + fmaxf(a1 + b3v.y, 0.f) * w4v.y
          + fmaxf(a2 + b3v.z, 0.f) * w4v.z
          + fmaxf(a3 + b3v.w, 0.f) * w4v.w;
  red[tid] = p;
  __syncthreads();
  if (tid < 16) {
    float s = 0.f;
    #pragma unroll
    for (int i = 0; i < 16; ++i) s += red[i*16 + tid];
    out[m0 + tid] = s + b4[0];
  }
}

extern "C" void kernel_launch(void* const* d_in, const int* in_sizes, int n_in,
                              void* d_out, int out_size, void* d_ws, size_t ws_size,
                              hipStream_t stream) {
  const float* x    = (const float*)d_in[0];
  const float* w1   = (const float*)d_in[1];
  const float* b1   = (const float*)d_in[2];
  const float* chw  = (const float*)d_in[3];
  const float* chb  = (const float*)d_in[4];
  const float* gnw  = (const float*)d_in[5];
  const float* gnb  = (const float*)d_in[6];
  const float* wq   = (const float*)d_in[7];
  const float* bq   = (const float*)d_in[8];
  const float* wk   = (const float*)d_in[9];
  const float* bk   = (const float*)d_in[10];
  const float* wv   = (const float*)d_in[11];
  const float* bv   = (const float*)d_in[12];
  const float* wp   = (const float*)d_in[13];
  const float* bp   = (const float*)d_in[14];
  const float* ch2w = (const float*)d_in[15];
  const float* ch2b = (const float*)d_in[16];
  const float* w2   = (const float*)d_in[17];
  const float* b2   = (const float*)d_in[18];
  const float* w3   = (const float*)d_in[19];
  const float* b3   = (const float*)d_in[20];
  const float* w4   = (const float*)d_in[21];
  const float* b4   = (const float*)d_in[22];
  (void)bk; (void)in_sizes; (void)n_in; (void)out_size; (void)ws_size;

  float* ws = (float*)d_ws;
  float* c2 = ws + WS_C2;
  float* z1 = ws + WS_Z1;
  float* out = (float*)d_out;

  hipLaunchKernelGGL(k0_precompute, dim3(34), dim3(256), 0, stream,
                     wq, bq, wk, bk, wv, bv, wp, bp, ws);
  hipLaunchKernelGGL(k1_sample, dim3(4096), dim3(384), 0, stream,
                     x, w1, b1, chw, chb, gnw, gnb, ch2w, ch2b, ws, c2);
  hipLaunchKernelGGL(k2_fc1, dim3(32, 12), dim3(256), 0, stream, c2, w2, b2, z1);
  hipLaunchKernelGGL(k3_fc23, dim3(256), dim3(256), 0, stream, z1, w3, b3, w4, b4, out);
}

// Round 3
// 3950.159 us; speedup vs baseline: 1.2545x; 1.2545x over previous
//
#include <hip/hip_runtime.h>

// ws layout (floats)
#define WS_GX   0                       // 4096: Gx[cp][c] = alpha*sum_o wk[o][c]*wq[o][cp]
#define WS_CPV  4096                    // 4096: Cpvx[c][o] = sum_m wp[o][m]*wv[m][c]
#define WS_QB   8192                    // 64:   alpha * Wk^T bq
#define WS_BPV  8256                    // 64:   Wp bv + bp
#define WS_C2   8448                    // 4096*1536 conv2 output (flattened fc input)
#define WS_Z1   (8448 + 4096*1536)      // 4096*768 fc1 output

// ---------------- K0: tiny precompute of fused weight products ----------------
__global__ void k0_precompute(const float* __restrict__ wq, const float* __restrict__ bq,
                              const float* __restrict__ wk, const float* __restrict__ bk,
                              const float* __restrict__ wv, const float* __restrict__ bv,
                              const float* __restrict__ wp, const float* __restrict__ bp,
                              float* __restrict__ ws) {
  int idx = blockIdx.x * 256 + threadIdx.x;
  const float ALPHA = 0.125f * 1.4426950408889634f;  // C^-0.5 * log2(e), folded into scores
  if (idx < 4096) {
    int cp = idx >> 6, c = idx & 63;
    float s = 0.f;
    for (int o = 0; o < 64; ++o) s += wk[o*64 + c] * wq[o*64 + cp];
    ws[WS_GX + idx] = s * ALPHA;
  } else if (idx < 8192) {
    int i = idx - 4096; int c = i >> 6, o = i & 63;
    float s = 0.f;
    for (int m = 0; m < 64; ++m) s += wp[o*64 + m] * wv[m*64 + c];
    ws[WS_CPV + i] = s;
  } else if (idx < 8256) {
    int c = idx - 8192;
    float s = 0.f;
    for (int o = 0; o < 64; ++o) s += wk[o*64 + c] * bq[o];
    ws[WS_QB + c] = s * ALPHA;
  } else if (idx < 8320) {
    int o = idx - 8256;
    float s = bp[o];
    for (int m = 0; m < 64; ++m) s += wp[o*64 + m] * bv[m];
    ws[WS_BPV + o] = s;
  }
}

// ---------------- K1: per-sample pipeline (conv1 -> GN -> attention -> conv2) ----------------
// block = 384 threads; thread = (token-slot ts = tid>>2 handling tokens {ts, ts+96},
// quarter q = tid&3 owning channels q*16..q*16+15).
// F=8 fma per b128 read (2 tokens x 4 u) -> VALU-bound even at ~4cyc/b128.
// Hs row placement: rowBase(c) = c*196 + ((c>>4)&3)*4 -> the 4 quarters' rows start at
// banks offset by 4, so the wave's 4 distinct b128 broadcast addresses occupy 4 DISJOINT
// 4-bank groups -> zero bank conflicts (the R2 bug: quarters aliased to the same banks).
__launch_bounds__(384, 2)
__global__ void k1_sample(const float* __restrict__ x,
                          const float* __restrict__ w1, const float* __restrict__ b1,
                          const float* __restrict__ chw, const float* __restrict__ chb,
                          const float* __restrict__ gnw, const float* __restrict__ gnb,
                          const float* __restrict__ ch2w, const float* __restrict__ ch2b,
                          const float* __restrict__ ws, float* __restrict__ c2out) {
  __shared__ float Hs[12556];          // rowBase(63)+196 = 12556 floats
  __shared__ float redS[384];
  __shared__ float redQ[384];
  __shared__ float scS[64];
  __shared__ float shS[64];

  const int tid = threadIdx.x;
  const int ts  = tid >> 2;            // token slot 0..95
  const int q   = tid & 3;             // quarter 0..3
  const int c0  = q * 16;              // my channel base
  const int t0  = ts, t1 = ts + 96;    // my two tokens
  const int qbase = q * 3140;          // rowBase(c0+j) = qbase + 196*j
  const int b   = blockIdx.x;

  const float x0 = x[b*3+0], x1 = x[b*3+1], x2 = x[b*3+2];

  // conv-input window for token t: hv[dy*3+dx] = h1[y+dy-1][xx+dx-1], zero-padded
  auto mk_window = [&](int t, float* hv) {
    int y = t >> 6, xx = t & 63;
    #pragma unroll
    for (int dy = 0; dy < 3; ++dy) {
      int r = y + dy - 1;
      bool rv = (r >= 0) && (r < 3);
      float xr = (r == 0) ? x0 : ((r == 1) ? x1 : x2);
      #pragma unroll
      for (int dx = 0; dx < 3; ++dx) {
        int cc = xx + dx - 1;
        bool cv = (cc >= 0) && (cc < 64);
        float w1v = cv ? w1[cc] : 0.f;
        float b1v = cv ? b1[cc] : 0.f;
        hv[dy*3+dx] = rv ? fmaf(xr, w1v, cv ? b1v : 0.f) : 0.f;
      }
    }
  };

  // ---- conv1 (1->64): write my 16 channels for both tokens ----
  {
    float hv0[9], hv1[9];
    mk_window(t0, hv0);
    mk_window(t1, hv1);
    #pragma unroll
    for (int j = 0; j < 16; ++j) {
      int c = c0 + j;
      float a0 = chb[c], a1 = a0;
      #pragma unroll
      for (int k = 0; k < 9; ++k) {
        float w = chw[c*9+k];
        a0 = fmaf(w, hv0[k], a0);
        a1 = fmaf(w, hv1[k], a1);
      }
      Hs[qbase + 196*j + t0] = a0;
      Hs[qbase + 196*j + t1] = a1;
    }
  }
  __syncthreads();

  // ---- instance-norm stats: thread handles channel c=tid&63, segment seg=tid>>6 ----
  {
    int c = tid & 63, seg = tid >> 6;
    int rb = c*196 + ((c>>4)&3)*4;
    float s = 0.f, qq = 0.f;
    for (int u = 0; u < 32; ++u) {
      int uu = (u + c) & 31;           // skew: decorrelate banks across lanes
      float v = Hs[rb + seg*32 + uu];
      s += v; qq = fmaf(v, v, qq);
    }
    redS[tid] = s; redQ[tid] = qq;
  }
  __syncthreads();
  if (tid < 64) {
    float s = 0.f, qq = 0.f;
    #pragma unroll
    for (int g = 0; g < 6; ++g) { s += redS[g*64 + tid]; qq += redQ[g*64 + tid]; }
    float mu  = s * (1.f/192.f);
    float var = qq * (1.f/192.f) - mu*mu;
    float rs  = rsqrtf(var + 1e-5f);
    float sc  = gnw[tid] * rs;
    scS[tid] = sc;
    shS[tid] = gnb[tid] - mu * sc;
  }
  __syncthreads();
  // normalize my own entries
  #pragma unroll
  for (int j = 0; j < 16; ++j) {
    int c = c0 + j, a = qbase + 196*j;
    Hs[a + t0] = fmaf(Hs[a + t0], scS[c], shS[c]);
    Hs[a + t1] = fmaf(Hs[a + t1], scS[c], shS[c]);
  }
  __syncthreads();

  // ---- attention ----
  const float* __restrict__ Gx  = ws + WS_GX;
  const float* __restrict__ qb  = ws + WS_QB;
  const float* __restrict__ Cpv = ws + WS_CPV;
  const float* __restrict__ bpv = ws + WS_BPV;

  // q~ for my 16 channels, both tokens
  float qt0[16], qt1[16];
  #pragma unroll
  for (int j = 0; j < 16; ++j) { qt0[j] = qb[c0+j]; qt1[j] = qt0[j]; }
  for (int cp = 0; cp < 64; ++cp) {
    int rb = cp*196 + ((cp>>4)&3)*4;
    float h0 = Hs[rb + t0];
    float h1 = Hs[rb + t1];
    const float4* g4 = (const float4*)(Gx + cp*64 + c0);
    #pragma unroll
    for (int i = 0; i < 4; ++i) {
      float4 g = g4[i];
      qt0[4*i+0] = fmaf(g.x, h0, qt0[4*i+0]); qt1[4*i+0] = fmaf(g.x, h1, qt1[4*i+0]);
      qt0[4*i+1] = fmaf(g.y, h0, qt0[4*i+1]); qt1[4*i+1] = fmaf(g.y, h1, qt1[4*i+1]);
      qt0[4*i+2] = fmaf(g.z, h0, qt0[4*i+2]); qt1[4*i+2] = fmaf(g.z, h1, qt1[4*i+2]);
      qt0[4*i+3] = fmaf(g.w, h0, qt0[4*i+3]); qt1[4*i+3] = fmaf(g.w, h1, qt1[4*i+3]);
    }
  }

  // online softmax + g = attn @ h for both tokens
  float ga0[16], ga1[16];
  #pragma unroll
  for (int j = 0; j < 16; ++j) { ga0[j] = 0.f; ga1[j] = 0.f; }
  float m0v = -1e30f, l0v = 0.f, m1v = -1e30f, l1v = 0.f;

  for (int u0 = 0; u0 < 192; u0 += 4) {
    float a00=0.f,a01=0.f,a02=0.f,a03=0.f;
    float a10=0.f,a11=0.f,a12=0.f,a13=0.f;
    #pragma unroll
    for (int j = 0; j < 16; ++j) {
      const float4 h4 = *(const float4*)&Hs[qbase + 196*j + u0];
      float q0 = qt0[j], q1 = qt1[j];
      a00 = fmaf(q0, h4.x, a00); a01 = fmaf(q0, h4.y, a01);
      a02 = fmaf(q0, h4.z, a02); a03 = fmaf(q0, h4.w, a03);
      a10 = fmaf(q1, h4.x, a10); a11 = fmaf(q1, h4.y, a11);
      a12 = fmaf(q1, h4.z, a12); a13 = fmaf(q1, h4.w, a13);
    }
    // combine the 4 quarters (lanes 4ts..4ts+3)
    a00 += __shfl_xor(a00,1); a00 += __shfl_xor(a00,2);
    a01 += __shfl_xor(a01,1); a01 += __shfl_xor(a01,2);
    a02 += __shfl_xor(a02,1); a02 += __shfl_xor(a02,2);
    a03 += __shfl_xor(a03,1); a03 += __shfl_xor(a03,2);
    a10 += __shfl_xor(a10,1); a10 += __shfl_xor(a10,2);
    a11 += __shfl_xor(a11,1); a11 += __shfl_xor(a11,2);
    a12 += __shfl_xor(a12,1); a12 += __shfl_xor(a12,2);
    a13 += __shfl_xor(a13,1); a13 += __shfl_xor(a13,2);

    float mn0 = fmaxf(fmaxf(fmaxf(a00,a01), fmaxf(a02,a03)), m0v);
    float al0 = __builtin_exp2f(m0v - mn0);
    float p00 = __builtin_exp2f(a00 - mn0);
    float p01 = __builtin_exp2f(a01 - mn0);
    float p02 = __builtin_exp2f(a02 - mn0);
    float p03 = __builtin_exp2f(a03 - mn0);
    l0v = fmaf(l0v, al0, (p00+p01)+(p02+p03));
    m0v = mn0;

    float mn1 = fmaxf(fmaxf(fmaxf(a10,a11), fmaxf(a12,a13)), m1v);
    float al1 = __builtin_exp2f(m1v - mn1);
    float p10 = __builtin_exp2f(a10 - mn1);
    float p11 = __builtin_exp2f(a11 - mn1);
    float p12 = __builtin_exp2f(a12 - mn1);
    float p13 = __builtin_exp2f(a13 - mn1);
    l1v = fmaf(l1v, al1, (p10+p11)+(p12+p13));
    m1v = mn1;

    #pragma unroll
    for (int j = 0; j < 16; ++j) {
      const float4 h4 = *(const float4*)&Hs[qbase + 196*j + u0];
      float g0 = ga0[j] * al0;
      g0 = fmaf(p00, h4.x, g0); g0 = fmaf(p01, h4.y, g0);
      g0 = fmaf(p02, h4.z, g0); g0 = fmaf(p03, h4.w, g0);
      ga0[j] = g0;
      float g1 = ga1[j] * al1;
      g1 = fmaf(p10, h4.x, g1); g1 = fmaf(p11, h4.y, g1);
      g1 = fmaf(p12, h4.z, g1); g1 = fmaf(p13, h4.w, g1);
      ga1[j] = g1;
    }
  }
  {
    float r0 = 1.f / l0v, r1 = 1.f / l1v;
    #pragma unroll
    for (int j = 0; j < 16; ++j) { ga0[j] *= r0; ga1[j] *= r1; }
  }

  // p[o] = bpv[o] + sum_c Cpv[c][o]*g[c]; 4 o-chunks of 16, combined over quarters
  float keep0[16], keep1[16];
  #pragma unroll
  for (int chunk = 0; chunk < 4; ++chunk) {
    float p0[16], p1[16];
    #pragma unroll
    for (int o = 0; o < 16; ++o) { p0[o] = 0.f; p1[o] = 0.f; }
    #pragma unroll
    for (int j = 0; j < 16; ++j) {
      float g0 = ga0[j], g1 = ga1[j];
      const float4* c4 = (const float4*)(Cpv + (c0+j)*64 + chunk*16);
      #pragma unroll
      for (int i = 0; i < 4; ++i) {
        float4 cv = c4[i];
        p0[4*i+0] = fmaf(cv.x, g0, p0[4*i+0]); p1[4*i+0] = fmaf(cv.x, g1, p1[4*i+0]);
        p0[4*i+1] = fmaf(cv.y, g0, p0[4*i+1]); p1[4*i+1] = fmaf(cv.y, g1, p1[4*i+1]);
        p0[4*i+2] = fmaf(cv.z, g0, p0[4*i+2]); p1[4*i+2] = fmaf(cv.z, g1, p1[4*i+2]);
        p0[4*i+3] = fmaf(cv.w, g0, p0[4*i+3]); p1[4*i+3] = fmaf(cv.w, g1, p1[4*i+3]);
      }
    }
    #pragma unroll
    for (int o = 0; o < 16; ++o) {
      float c00 = p0[o]; c00 += __shfl_xor(c00,1); c00 += __shfl_xor(c00,2);
      float c11 = p1[o]; c11 += __shfl_xor(c11,1); c11 += __shfl_xor(c11,2);
      if (q == chunk) { keep0[o] = c00; keep1[o] = c11; }
    }
  }
  #pragma unroll
  for (int o = 0; o < 16; ++o) {
    keep0[o] += bpv[c0 + o];
    keep1[o] += bpv[c0 + o];
  }

  __syncthreads();   // attention reads of Hs complete before overwrite

  // ---- residual: res = conv1 (recomputed) + attention output ----
  {
    float hv0[9], hv1[9];
    mk_window(t0, hv0);
    mk_window(t1, hv1);
    #pragma unroll
    for (int j = 0; j < 16; ++j) {
      int c = c0 + j;
      float a0 = chb[c], a1 = a0;
      #pragma unroll
      for (int k = 0; k < 9; ++k) {
        float w = chw[c*9+k];
        a0 = fmaf(w, hv0[k], a0);
        a1 = fmaf(w, hv1[k], a1);
      }
      Hs[qbase + 196*j + t0] = a0 + keep0[j];
      Hs[qbase + 196*j + t1] = a1 + keep1[j];
    }
  }
  __syncthreads();

  // ---- conv2 (64->8): thread computes oc {2q, 2q+1} for its two tokens ----
  {
    const int oc0 = 2*q, oc1 = 2*q + 1;
    float o00 = ch2b[oc0], o01 = ch2b[oc1];  // token t0
    float o10 = ch2b[oc0], o11 = ch2b[oc1];  // token t1
    const int y0 = t0 >> 6, xx0 = t0 & 63;
    const int y1 = t1 >> 6, xx1 = t1 & 63;
    for (int c = 0; c < 64; ++c) {
      int rb = c*196 + ((c>>4)&3)*4;
      float win0[9], win1[9];
      #pragma unroll
      for (int dy = 0; dy < 3; ++dy) {
        int r0 = y0 + dy - 1, r1 = y1 + dy - 1;
        bool rv0 = (r0 >= 0) && (r0 < 3);
        bool rv1 = (r1 >= 0) && (r1 < 3);
        #pragma unroll
        for (int dx = 0; dx < 3; ++dx) {
          int cc0 = xx0 + dx - 1, cc1 = xx1 + dx - 1;
          bool cv0 = (cc0 >= 0) && (cc0 < 64);
          bool cv1 = (cc1 >= 0) && (cc1 < 64);
          win0[dy*3+dx] = (rv0 && cv0) ? Hs[rb + r0*64 + cc0] : 0.f;
          win1[dy*3+dx] = (rv1 && cv1) ? Hs[rb + r1*64 + cc1] : 0.f;
        }
      }
      const float* wA = ch2w + oc0*576 + c*9;
      const float* wB = ch2w + oc1*576 + c*9;
      #pragma unroll
      for (int k = 0; k < 9; ++k) {
        float wa = wA[k], wb = wB[k];
        o00 = fmaf(wa, win0[k], o00); o01 = fmaf(wb, win0[k], o01);
        o10 = fmaf(wa, win1[k], o10); o11 = fmaf(wb, win1[k], o11);
      }
    }
    c2out[b*1536 + oc0*192 + t0] = o00;
    c2out[b*1536 + oc1*192 + t0] = o01;
    c2out[b*1536 + oc0*192 + t1] = o10;
    c2out[b*1536 + oc1*192 + t1] = o11;
  }
}

// ---------------- K2: fc1 GEMM  z1[4096][768] = relu(c2[4096][1536] @ w2^T + b2) ----------------
__launch_bounds__(256, 4)
__global__ void k2_fc1(const float* __restrict__ A, const float* __restrict__ w2,
                       const float* __restrict__ b2, float* __restrict__ z1) {
  __shared__ float As[128 * 33];
  __shared__ float Bs[32 * 68];
  const int tid = threadIdx.x;
  const int m0 = blockIdx.x * 128;
  const int n0 = blockIdx.y * 64;
  const int tm = tid & 15, tn = tid >> 4;   // tn 0..15

  float acc[8][4];
  #pragma unroll
  for (int i = 0; i < 8; ++i)
    #pragma unroll
    for (int j = 0; j < 4; ++j) acc[i][j] = 0.f;

  for (int k0 = 0; k0 < 1536; k0 += 32) {
    #pragma unroll
    for (int i = 0; i < 4; ++i) {   // stage A 128x32
      int j = tid + i*256;
      int mm = j >> 3, k4 = (j & 7) << 2;
      float4 v = *(const float4*)&A[(m0+mm)*1536 + k0 + k4];
      As[mm*33 + k4+0] = v.x; As[mm*33 + k4+1] = v.y;
      As[mm*33 + k4+2] = v.z; As[mm*33 + k4+3] = v.w;
    }
    #pragma unroll
    for (int i = 0; i < 2; ++i) {   // stage B 64x32 transposed -> Bs[k][68]
      int j = tid + i*256;
      int nn = j >> 3, k4 = (j & 7) << 2;
      float4 v = *(const float4*)&w2[(n0+nn)*1536 + k0 + k4];
      Bs[(k4+0)*68 + nn] = v.x; Bs[(k4+1)*68 + nn] = v.y;
      Bs[(k4+2)*68 + nn] = v.z; Bs[(k4+3)*68 + nn] = v.w;
    }
    __syncthreads();
    #pragma unroll
    for (int k = 0; k < 32; ++k) {
      float a[8];
      #pragma unroll
      for (int i = 0; i < 8; ++i) a[i] = As[(tm + 16*i)*33 + k];
      float4 bv = *(const float4*)&Bs[k*68 + tn*4];
      #pragma unroll
      for (int i = 0; i < 8; ++i) {
        acc[i][0] = fmaf(a[i], bv.x, acc[i][0]);
        acc[i][1] = fmaf(a[i], bv.y, acc[i][1]);
        acc[i][2] = fmaf(a[i], bv.z, acc[i][2]);
        acc[i][3] = fmaf(a[i], bv.w, acc[i][3]);
      }
    }
    __syncthreads();
  }
  float4 bb = *(const float4*)&b2[n0 + tn*4];
  #pragma unroll
  for (int i = 0; i < 8; ++i) {
    float4 r;
    r.x = fmaxf(acc[i][0] + bb.x, 0.f);
    r.y = fmaxf(acc[i][1] + bb.y, 0.f);
    r.z = fmaxf(acc[i][2] + bb.z, 0.f);
    r.w = fmaxf(acc[i][3] + bb.w, 0.f);
    *(float4*)&z1[(m0 + tm + 16*i)*768 + n0 + tn*4] = r;
  }
}

// ---------------- K3: fc2+relu+fc3  out[b] = b4 + sum_o w4[o]*relu(b3[o] + w3[o].z1[b]) ----------------
__launch_bounds__(256, 2)
__global__ void k3_fc23(const float* __restrict__ z1, const float* __restrict__ w3,
                        const float* __restrict__ b3, const float* __restrict__ w4,
                        const float* __restrict__ b4, float* __restrict__ out) {
  __shared__ float Zs[16 * 772];
  __shared__ float Ws[32 * 68];
  __shared__ float red[256];
  const int tid = threadIdx.x;
  const int m0 = blockIdx.x * 16;
  const int tm = tid & 15, tn = tid >> 4;   // tn 0..15 -> 4 fc2 outputs each

  #pragma unroll
  for (int i = 0; i < 12; ++i) {   // stage Zs 16x768
    int j = tid + i*256;
    int mm = j / 192;
    int kq = j - mm*192;
    float4 v = *(const float4*)&z1[(m0+mm)*768 + kq*4];
    *(float4*)&Zs[mm*772 + kq*4] = v;
  }

  float a0 = 0.f, a1 = 0.f, a2 = 0.f, a3 = 0.f;
  for (int k0 = 0; k0 < 768; k0 += 32) {
    __syncthreads();
    #pragma unroll
    for (int i = 0; i < 2; ++i) {  // stage Ws[32k][68] transposed from w3[n][k]
      int j = tid + i*256;
      int nn = j >> 3, k4 = (j & 7) << 2;
      float4 v = *(const float4*)&w3[nn*768 + k0 + k4];
      Ws[(k4+0)*68 + nn] = v.x; Ws[(k4+1)*68 + nn] = v.y;
      Ws[(k4+2)*68 + nn] = v.z; Ws[(k4+3)*68 + nn] = v.w;
    }
    __syncthreads();
    #pragma unroll
    for (int k = 0; k < 32; k += 4) {
      float4 z  = *(const float4*)&Zs[tm*772 + k0 + k];
      float4 w0 = *(const float4*)&Ws[(k+0)*68 + tn*4];
      float4 w1v= *(const float4*)&Ws[(k+1)*68 + tn*4];
      float4 w2v= *(const float4*)&Ws[(k+2)*68 + tn*4];
      float4 w3v= *(const float4*)&Ws[(k+3)*68 + tn*4];
      a0 = fmaf(z.x, w0.x, a0); a1 = fmaf(z.x, w0.y, a1); a2 = fmaf(z.x, w0.z, a2); a3 = fmaf(z.x, w0.w, a3);
      a0 = fmaf(z.y, w1v.x, a0); a1 = fmaf(z.y, w1v.y, a1); a2 = fmaf(z.y, w1v.z, a2); a3 = fmaf(z.y, w1v.w, a3);
      a0 = fmaf(z.z, w2v.x, a0); a1 = fmaf(z.z, w2v.y, a1); a2 = fmaf(z.z, w2v.z, a2); a3 = fmaf(z.z, w2v.w, a3);
      a0 = fmaf(z.w, w3v.x, a0); a1 = fmaf(z.w, w3v.y, a1); a2 = fmaf(z.w, w3v.z, a2); a3 = fmaf(z.w, w3v.w, a3);
    }
  }
  float4 b3v = *(const float4*)&b3[tn*4];
  float4 w4v = *(const float4*)&w4[tn*4];
  float p = fmaxf(a0 + b3v.x, 0.f) * w4v.x
          + fmaxf(a1 + b3v.y, 0.f) * w4v.y
          + fmaxf(a2 + b3v.z, 0.f) * w4v.z
          + fmaxf(a3 + b3v.w, 0.f) * w4v.w;
  red[tid] = p;
  __syncthreads();
  if (tid < 16) {
    float s = 0.f;
    #pragma unroll
    for (int i = 0; i < 16; ++i) s += red[i*16 + tid];
    out[m0 + tid] = s + b4[0];
  }
}

extern "C" void kernel_launch(void* const* d_in, const int* in_sizes, int n_in,
                              void* d_out, int out_size, void* d_ws, size_t ws_size,
                              hipStream_t stream) {
  const float* x    = (const float*)d_in[0];
  const float* w1   = (const float*)d_in[1];
  const float* b1   = (const float*)d_in[2];
  const float* chw  = (const float*)d_in[3];
  const float* chb  = (const float*)d_in[4];
  const float* gnw  = (const float*)d_in[5];
  const float* gnb  = (const float*)d_in[6];
  const float* wq   = (const float*)d_in[7];
  const float* bq   = (const float*)d_in[8];
  const float* wk   = (const float*)d_in[9];
  const float* bk   = (const float*)d_in[10];
  const float* wv   = (const float*)d_in[11];
  const float* bv   = (const float*)d_in[12];
  const float* wp   = (const float*)d_in[13];
  const float* bp   = (const float*)d_in[14];
  const float* ch2w = (const float*)d_in[15];
  const float* ch2b = (const float*)d_in[16];
  const float* w2   = (const float*)d_in[17];
  const float* b2   = (const float*)d_in[18];
  const float* w3   = (const float*)d_in[19];
  const float* b3   = (const float*)d_in[20];
  const float* w4   = (const float*)d_in[21];
  const float* b4   = (const float*)d_in[22];
  (void)bk; (void)in_sizes; (void)n_in; (void)out_size; (void)ws_size;

  float* ws = (float*)d_ws;
  float* c2 = ws + WS_C2;
  float* z1 = ws + WS_Z1;
  float* out = (float*)d_out;

  hipLaunchKernelGGL(k0_precompute, dim3(34), dim3(256), 0, stream,
                     wq, bq, wk, bk, wv, bv, wp, bp, ws);
  hipLaunchKernelGGL(k1_sample, dim3(4096), dim3(384), 0, stream,
                     x, w1, b1, chw, chb, gnw, gnb, ch2w, ch2b, ws, c2);
  hipLaunchKernelGGL(k2_fc1, dim3(32, 12), dim3(256), 0, stream, c2, w2, b2, z1);
  hipLaunchKernelGGL(k3_fc23, dim3(256), dim3(256), 0, stream, z1, w3, b3, w4, b4, out);
}

// Round 4
// 3483.523 us; speedup vs baseline: 1.4226x; 1.1340x over previous
//
#include <hip/hip_runtime.h>

// ws layout (floats)
#define WS_GX   0                       // 4096: Gx[cp][c] = alpha*sum_o wk[o][c]*wq[o][cp]
#define WS_CPV  4096                    // 4096: Cpvx[c][o] = sum_m wp[o][m]*wv[m][c]
#define WS_QB   8192                    // 64:   alpha * Wk^T bq
#define WS_BPV  8256                    // 64:   Wp bv + bp
#define WS_C2   8448                    // 4096*1536 conv2 output (flattened fc input)
#define WS_Z1   (8448 + 4096*1536)      // 4096*768 fc1 output

// ---------------- K0: tiny precompute of fused weight products ----------------
__global__ void k0_precompute(const float* __restrict__ wq, const float* __restrict__ bq,
                              const float* __restrict__ wk, const float* __restrict__ bk,
                              const float* __restrict__ wv, const float* __restrict__ bv,
                              const float* __restrict__ wp, const float* __restrict__ bp,
                              float* __restrict__ ws) {
  int idx = blockIdx.x * 256 + threadIdx.x;
  const float ALPHA = 0.125f * 1.4426950408889634f;  // C^-0.5 * log2(e), folded into scores
  if (idx < 4096) {
    int cp = idx >> 6, c = idx & 63;
    float s = 0.f;
    for (int o = 0; o < 64; ++o) s += wk[o*64 + c] * wq[o*64 + cp];
    ws[WS_GX + idx] = s * ALPHA;
  } else if (idx < 8192) {
    int i = idx - 4096; int c = i >> 6, o = i & 63;
    float s = 0.f;
    for (int m = 0; m < 64; ++m) s += wp[o*64 + m] * wv[m*64 + c];
    ws[WS_CPV + i] = s;
  } else if (idx < 8256) {
    int c = idx - 8192;
    float s = 0.f;
    for (int o = 0; o < 64; ++o) s += wk[o*64 + c] * bq[o];
    ws[WS_QB + c] = s * ALPHA;
  } else if (idx < 8320) {
    int o = idx - 8256;
    float s = bp[o];
    for (int m = 0; m < 64; ++m) s += wp[o*64 + m] * bv[m];
    ws[WS_BPV + o] = s;
  }
}

// ---------------- K1: per-sample pipeline (conv1 -> GN -> attention -> conv2) ----------------
// block = 384 threads; thread = (token-slot ts = tid>>2 handling tokens {ts, ts+96},
// quarter q = tid&3 owning channels q*16..q*16+15).
// Hs row placement: rowBase(c) = c*196 + ((c>>4)&3)*4 -> bank-disjoint quarters (R3 fix).
// R4 fixes vs R3 (spill elimination):
//  - no max-tracking in softmax (scores analytically ~0.04; exp2 safe) -> no alpha rescale
//  - gacc loop re-reads h4 via laundered index (asm) so 16 float4 aren't kept live
//  - Cpv phase via LDS round-trip of g (Hs rows are dead after attention) -> no shfl arrays
__launch_bounds__(384, 3)
__global__ void k1_sample(const float* __restrict__ x,
                          const float* __restrict__ w1, const float* __restrict__ b1,
                          const float* __restrict__ chw, const float* __restrict__ chb,
                          const float* __restrict__ gnw, const float* __restrict__ gnb,
                          const float* __restrict__ ch2w, const float* __restrict__ ch2b,
                          const float* __restrict__ ws, float* __restrict__ c2out) {
  __shared__ float Hs[12556];          // rowBase(63)+196 = 12556 floats
  __shared__ float redS[384];
  __shared__ float redQ[384];
  __shared__ float scS[64];
  __shared__ float shS[64];

  const int tid = threadIdx.x;
  const int ts  = tid >> 2;            // token slot 0..95
  const int q   = tid & 3;             // quarter 0..3
  const int c0  = q * 16;              // my channel base
  const int t0  = ts, t1 = ts + 96;    // my two tokens
  const int qbase = q * 3140;          // rowBase(c0+j) = qbase + 196*j
  const int b   = blockIdx.x;

  const float x0 = x[b*3+0], x1 = x[b*3+1], x2 = x[b*3+2];

  // conv-input window for token t: hv[dy*3+dx] = h1[y+dy-1][xx+dx-1], zero-padded
  auto mk_window = [&](int t, float* hv) {
    int y = t >> 6, xx = t & 63;
    #pragma unroll
    for (int dy = 0; dy < 3; ++dy) {
      int r = y + dy - 1;
      bool rv = (r >= 0) && (r < 3);
      float xr = (r == 0) ? x0 : ((r == 1) ? x1 : x2);
      #pragma unroll
      for (int dx = 0; dx < 3; ++dx) {
        int cc = xx + dx - 1;
        bool cv = (cc >= 0) && (cc < 64);
        float w1v = cv ? w1[cc] : 0.f;
        float b1v = cv ? b1[cc] : 0.f;
        hv[dy*3+dx] = rv ? fmaf(xr, w1v, cv ? b1v : 0.f) : 0.f;
      }
    }
  };

  // ---- conv1 (1->64): write my 16 channels for both tokens ----
  {
    float hv0[9], hv1[9];
    mk_window(t0, hv0);
    mk_window(t1, hv1);
    #pragma unroll
    for (int j = 0; j < 16; ++j) {
      int c = c0 + j;
      float a0 = chb[c], a1 = a0;
      #pragma unroll
      for (int k = 0; k < 9; ++k) {
        float w = chw[c*9+k];
        a0 = fmaf(w, hv0[k], a0);
        a1 = fmaf(w, hv1[k], a1);
      }
      Hs[qbase + 196*j + t0] = a0;
      Hs[qbase + 196*j + t1] = a1;
    }
  }
  __syncthreads();

  // ---- instance-norm stats: thread handles channel c=tid&63, segment seg=tid>>6 ----
  {
    int c = tid & 63, seg = tid >> 6;
    int rb = c*196 + ((c>>4)&3)*4;
    float s = 0.f, qq = 0.f;
    for (int u = 0; u < 32; ++u) {
      int uu = (u + c) & 31;           // skew: decorrelate banks across lanes
      float v = Hs[rb + seg*32 + uu];
      s += v; qq = fmaf(v, v, qq);
    }
    redS[tid] = s; redQ[tid] = qq;
  }
  __syncthreads();
  if (tid < 64) {
    float s = 0.f, qq = 0.f;
    #pragma unroll
    for (int g = 0; g < 6; ++g) { s += redS[g*64 + tid]; qq += redQ[g*64 + tid]; }
    float mu  = s * (1.f/192.f);
    float var = qq * (1.f/192.f) - mu*mu;
    float rs  = rsqrtf(var + 1e-5f);
    float sc  = gnw[tid] * rs;
    scS[tid] = sc;
    shS[tid] = gnb[tid] - mu * sc;
  }
  __syncthreads();
  // normalize my own entries
  #pragma unroll
  for (int j = 0; j < 16; ++j) {
    int c = c0 + j, a = qbase + 196*j;
    Hs[a + t0] = fmaf(Hs[a + t0], scS[c], shS[c]);
    Hs[a + t1] = fmaf(Hs[a + t1], scS[c], shS[c]);
  }
  __syncthreads();

  // ---- attention ----
  const float* __restrict__ Gx  = ws + WS_GX;
  const float* __restrict__ qb  = ws + WS_QB;
  const float* __restrict__ Cpv = ws + WS_CPV;
  const float* __restrict__ bpv = ws + WS_BPV;

  // q~ for my 16 channels, both tokens
  float qt0[16], qt1[16];
  #pragma unroll
  for (int j = 0; j < 16; ++j) { qt0[j] = qb[c0+j]; qt1[j] = qt0[j]; }
  for (int cp = 0; cp < 64; ++cp) {
    int rb = cp*196 + ((cp>>4)&3)*4;
    float h0 = Hs[rb + t0];
    float h1 = Hs[rb + t1];
    const float4* g4 = (const float4*)(Gx + cp*64 + c0);
    #pragma unroll
    for (int i = 0; i < 4; ++i) {
      float4 g = g4[i];
      qt0[4*i+0] = fmaf(g.x, h0, qt0[4*i+0]); qt1[4*i+0] = fmaf(g.x, h1, qt1[4*i+0]);
      qt0[4*i+1] = fmaf(g.y, h0, qt0[4*i+1]); qt1[4*i+1] = fmaf(g.y, h1, qt1[4*i+1]);
      qt0[4*i+2] = fmaf(g.z, h0, qt0[4*i+2]); qt1[4*i+2] = fmaf(g.z, h1, qt1[4*i+2]);
      qt0[4*i+3] = fmaf(g.w, h0, qt0[4*i+3]); qt1[4*i+3] = fmaf(g.w, h1, qt1[4*i+3]);
    }
  }

  // softmax (no max subtraction: scores are O(0.05), exp2 safe) + g = attn @ h
  float ga0[16], ga1[16];
  #pragma unroll
  for (int j = 0; j < 16; ++j) { ga0[j] = 0.f; ga1[j] = 0.f; }
  float l0v = 0.f, l1v = 0.f;

  for (int u0 = 0; u0 < 192; u0 += 4) {
    float a00=0.f,a01=0.f,a02=0.f,a03=0.f;
    float a10=0.f,a11=0.f,a12=0.f,a13=0.f;
    #pragma unroll
    for (int j = 0; j < 16; ++j) {
      const float4 h4 = *(const float4*)&Hs[qbase + 196*j + u0];
      float q0 = qt0[j], q1 = qt1[j];
      a00 = fmaf(q0, h4.x, a00); a01 = fmaf(q0, h4.y, a01);
      a02 = fmaf(q0, h4.z, a02); a03 = fmaf(q0, h4.w, a03);
      a10 = fmaf(q1, h4.x, a10); a11 = fmaf(q1, h4.y, a11);
      a12 = fmaf(q1, h4.z, a12); a13 = fmaf(q1, h4.w, a13);
    }
    // combine the 4 quarters (lanes 4ts..4ts+3; xor1/xor2 lower to DPP quad_perm)
    a00 += __shfl_xor(a00,1); a00 += __shfl_xor(a00,2);
    a01 += __shfl_xor(a01,1); a01 += __shfl_xor(a01,2);
    a02 += __shfl_xor(a02,1); a02 += __shfl_xor(a02,2);
    a03 += __shfl_xor(a03,1); a03 += __shfl_xor(a03,2);
    a10 += __shfl_xor(a10,1); a10 += __shfl_xor(a10,2);
    a11 += __shfl_xor(a11,1); a11 += __shfl_xor(a11,2);
    a12 += __shfl_xor(a12,1); a12 += __shfl_xor(a12,2);
    a13 += __shfl_xor(a13,1); a13 += __shfl_xor(a13,2);

    float p00 = __builtin_exp2f(a00);
    float p01 = __builtin_exp2f(a01);
    float p02 = __builtin_exp2f(a02);
    float p03 = __builtin_exp2f(a03);
    l0v += (p00+p01)+(p02+p03);
    float p10 = __builtin_exp2f(a10);
    float p11 = __builtin_exp2f(a11);
    float p12 = __builtin_exp2f(a12);
    float p13 = __builtin_exp2f(a13);
    l1v += (p10+p11)+(p12+p13);

    // launder u0 so the gacc loop's LDS reads can't be CSE'd with the score loop's
    // (prevents keeping 16 float4 live across the softmax -> no VGPR spill)
    int u0b = u0;
    asm volatile("" : "+v"(u0b));
    #pragma unroll
    for (int j = 0; j < 16; ++j) {
      const float4 h4 = *(const float4*)&Hs[qbase + 196*j + u0b];
      float g0 = ga0[j];
      g0 = fmaf(p00, h4.x, g0); g0 = fmaf(p01, h4.y, g0);
      g0 = fmaf(p02, h4.z, g0); g0 = fmaf(p03, h4.w, g0);
      ga0[j] = g0;
      float g1 = ga1[j];
      g1 = fmaf(p10, h4.x, g1); g1 = fmaf(p11, h4.y, g1);
      g1 = fmaf(p12, h4.z, g1); g1 = fmaf(p13, h4.w, g1);
      ga1[j] = g1;
    }
  }

  // normalize g and round-trip through LDS (Hs content is dead now)
  {
    float r0 = 1.f / l0v, r1 = 1.f / l1v;
    __syncthreads();   // all Hs reads (score/gacc/qt) complete before overwrite
    #pragma unroll
    for (int j = 0; j < 16; ++j) {
      int a = qbase + 196*j;
      Hs[a + t0] = ga0[j] * r0;
      Hs[a + t1] = ga1[j] * r1;
    }
  }
  __syncthreads();

  // p[c0+o] = bpv[c0+o] + sum_c Cpv[c][c0+o] * g[c]   (g read back from LDS)
  float keep0[16], keep1[16];
  #pragma unroll
  for (int o = 0; o < 16; ++o) { keep0[o] = bpv[c0+o]; keep1[o] = keep0[o]; }
  for (int c = 0; c < 64; ++c) {
    int rb = c*196 + ((c>>4)&3)*4;
    float g0 = Hs[rb + t0];
    float g1 = Hs[rb + t1];
    const float4* c4 = (const float4*)(Cpv + c*64 + c0);
    #pragma unroll
    for (int i = 0; i < 4; ++i) {
      float4 cv = c4[i];
      keep0[4*i+0] = fmaf(cv.x, g0, keep0[4*i+0]); keep1[4*i+0] = fmaf(cv.x, g1, keep1[4*i+0]);
      keep0[4*i+1] = fmaf(cv.y, g0, keep0[4*i+1]); keep1[4*i+1] = fmaf(cv.y, g1, keep1[4*i+1]);
      keep0[4*i+2] = fmaf(cv.z, g0, keep0[4*i+2]); keep1[4*i+2] = fmaf(cv.z, g1, keep1[4*i+2]);
      keep0[4*i+3] = fmaf(cv.w, g0, keep0[4*i+3]); keep1[4*i+3] = fmaf(cv.w, g1, keep1[4*i+3]);
    }
  }
  __syncthreads();   // all g reads complete before residual overwrite

  // ---- residual: res = conv1 (recomputed) + attention output ----
  {
    float hv0[9], hv1[9];
    mk_window(t0, hv0);
    mk_window(t1, hv1);
    #pragma unroll
    for (int j = 0; j < 16; ++j) {
      int c = c0 + j;
      float a0 = chb[c], a1 = a0;
      #pragma unroll
      for (int k = 0; k < 9; ++k) {
        float w = chw[c*9+k];
        a0 = fmaf(w, hv0[k], a0);
        a1 = fmaf(w, hv1[k], a1);
      }
      Hs[qbase + 196*j + t0] = a0 + keep0[j];
      Hs[qbase + 196*j + t1] = a1 + keep1[j];
    }
  }
  __syncthreads();

  // ---- conv2 (64->8): thread computes oc {2q, 2q+1} for its two tokens ----
  {
    const int oc0 = 2*q, oc1 = 2*q + 1;
    float o00 = ch2b[oc0], o01 = ch2b[oc1];  // token t0
    float o10 = ch2b[oc0], o11 = ch2b[oc1];  // token t1
    const int y0 = t0 >> 6, xx0 = t0 & 63;
    const int y1 = t1 >> 6, xx1 = t1 & 63;
    for (int c = 0; c < 64; ++c) {
      int rb = c*196 + ((c>>4)&3)*4;
      float win0[9], win1[9];
      #pragma unroll
      for (int dy = 0; dy < 3; ++dy) {
        int r0 = y0 + dy - 1, r1 = y1 + dy - 1;
        bool rv0 = (r0 >= 0) && (r0 < 3);
        bool rv1 = (r1 >= 0) && (r1 < 3);
        #pragma unroll
        for (int dx = 0; dx < 3; ++dx) {
          int cc0 = xx0 + dx - 1, cc1 = xx1 + dx - 1;
          bool cv0 = (cc0 >= 0) && (cc0 < 64);
          bool cv1 = (cc1 >= 0) && (cc1 < 64);
          win0[dy*3+dx] = (rv0 && cv0) ? Hs[rb + r0*64 + cc0] : 0.f;
          win1[dy*3+dx] = (rv1 && cv1) ? Hs[rb + r1*64 + cc1] : 0.f;
        }
      }
      const float* wA = ch2w + oc0*576 + c*9;
      const float* wB = ch2w + oc1*576 + c*9;
      #pragma unroll
      for (int k = 0; k < 9; ++k) {
        float wa = wA[k], wb = wB[k];
        o00 = fmaf(wa, win0[k], o00); o01 = fmaf(wb, win0[k], o01);
        o10 = fmaf(wa, win1[k], o10); o11 = fmaf(wb, win1[k], o11);
      }
    }
    c2out[b*1536 + oc0*192 + t0] = o00;
    c2out[b*1536 + oc1*192 + t0] = o01;
    c2out[b*1536 + oc0*192 + t1] = o10;
    c2out[b*1536 + oc1*192 + t1] = o11;
  }
}

// ---------------- K2: fc1 GEMM  z1[4096][768] = relu(c2[4096][1536] @ w2^T + b2) ----------------
__launch_bounds__(256, 4)
__global__ void k2_fc1(const float* __restrict__ A, const float* __restrict__ w2,
                       const float* __restrict__ b2, float* __restrict__ z1) {
  __shared__ float As[128 * 33];
  __shared__ float Bs[32 * 68];
  const int tid = threadIdx.x;
  const int m0 = blockIdx.x * 128;
  const int n0 = blockIdx.y * 64;
  const int tm = tid & 15, tn = tid >> 4;   // tn 0..15

  float acc[8][4];
  #pragma unroll
  for (int i = 0; i < 8; ++i)
    #pragma unroll
    for (int j = 0; j < 4; ++j) acc[i][j] = 0.f;

  for (int k0 = 0; k0 < 1536; k0 += 32) {
    #pragma unroll
    for (int i = 0; i < 4; ++i) {   // stage A 128x32
      int j = tid + i*256;
      int mm = j >> 3, k4 = (j & 7) << 2;
      float4 v = *(const float4*)&A[(m0+mm)*1536 + k0 + k4];
      As[mm*33 + k4+0] = v.x; As[mm*33 + k4+1] = v.y;
      As[mm*33 + k4+2] = v.z; As[mm*33 + k4+3] = v.w;
    }
    #pragma unroll
    for (int i = 0; i < 2; ++i) {   // stage B 64x32 transposed -> Bs[k][68]
      int j = tid + i*256;
      int nn = j >> 3, k4 = (j & 7) << 2;
      float4 v = *(const float4*)&w2[(n0+nn)*1536 + k0 + k4];
      Bs[(k4+0)*68 + nn] = v.x; Bs[(k4+1)*68 + nn] = v.y;
      Bs[(k4+2)*68 + nn] = v.z; Bs[(k4+3)*68 + nn] = v.w;
    }
    __syncthreads();
    #pragma unroll
    for (int k = 0; k < 32; ++k) {
      float a[8];
      #pragma unroll
      for (int i = 0; i < 8; ++i) a[i] = As[(tm + 16*i)*33 + k];
      float4 bv = *(const float4*)&Bs[k*68 + tn*4];
      #pragma unroll
      for (int i = 0; i < 8; ++i) {
        acc[i][0] = fmaf(a[i], bv.x, acc[i][0]);
        acc[i][1] = fmaf(a[i], bv.y, acc[i][1]);
        acc[i][2] = fmaf(a[i], bv.z, acc[i][2]);
        acc[i][3] = fmaf(a[i], bv.w, acc[i][3]);
      }
    }
    __syncthreads();
  }
  float4 bb = *(const float4*)&b2[n0 + tn*4];
  #pragma unroll
  for (int i = 0; i < 8; ++i) {
    float4 r;
    r.x = fmaxf(acc[i][0] + bb.x, 0.f);
    r.y = fmaxf(acc[i][1] + bb.y, 0.f);
    r.z = fmaxf(acc[i][2] + bb.z, 0.f);
    r.w = fmaxf(acc[i][3] + bb.w, 0.f);
    *(float4*)&z1[(m0 + tm + 16*i)*768 + n0 + tn*4] = r;
  }
}

// ---------------- K3: fc2+relu+fc3  out[b] = b4 + sum_o w4[o]*relu(b3[o] + w3[o].z1[b]) ----------------
__launch_bounds__(256, 2)
__global__ void k3_fc23(const float* __restrict__ z1, const float* __restrict__ w3,
                        const float* __restrict__ b3, const float* __restrict__ w4,
                        const float* __restrict__ b4, float* __restrict__ out) {
  __shared__ float Zs[16 * 772];
  __shared__ float Ws[32 * 68];
  __shared__ float red[256];
  const int tid = threadIdx.x;
  const int m0 = blockIdx.x * 16;
  const int tm = tid & 15, tn = tid >> 4;   // tn 0..15 -> 4 fc2 outputs each

  #pragma unroll
  for (int i = 0; i < 12; ++i) {   // stage Zs 16x768
    int j = tid + i*256;
    int mm = j / 192;
    int kq = j - mm*192;
    float4 v = *(const float4*)&z1[(m0+mm)*768 + kq*4];
    *(float4*)&Zs[mm*772 + kq*4] = v;
  }

  float a0 = 0.f, a1 = 0.f, a2 = 0.f, a3 = 0.f;
  for (int k0 = 0; k0 < 768; k0 += 32) {
    __syncthreads();
    #pragma unroll
    for (int i = 0; i < 2; ++i) {  // stage Ws[32k][68] transposed from w3[n][k]
      int j = tid + i*256;
      int nn = j >> 3, k4 = (j & 7) << 2;
      float4 v = *(const float4*)&w3[nn*768 + k0 + k4];
      Ws[(k4+0)*68 + nn] = v.x; Ws[(k4+1)*68 + nn] = v.y;
      Ws[(k4+2)*68 + nn] = v.z; Ws[(k4+3)*68 + nn] = v.w;
    }
    __syncthreads();
    #pragma unroll
    for (int k = 0; k < 32; k += 4) {
      float4 z  = *(const float4*)&Zs[tm*772 + k0 + k];
      float4 w0 = *(const float4*)&Ws[(k+0)*68 + tn*4];
      float4 w1v= *(const float4*)&Ws[(k+1)*68 + tn*4];
      float4 w2v= *(const float4*)&Ws[(k+2)*68 + tn*4];
      float4 w3v= *(const float4*)&Ws[(k+3)*68 + tn*4];
      a0 = fmaf(z.x, w0.x, a0); a1 = fmaf(z.x, w0.y, a1); a2 = fmaf(z.x, w0.z, a2); a3 = fmaf(z.x, w0.w, a3);
      a0 = fmaf(z.y, w1v.x, a0); a1 = fmaf(z.y, w1v.y, a1); a2 = fmaf(z.y, w1v.z, a2); a3 = fmaf(z.y, w1v.w, a3);
      a0 = fmaf(z.z, w2v.x, a0); a1 = fmaf(z.z, w2v.y, a1); a2 = fmaf(z.z, w2v.z, a2); a3 = fmaf(z.z, w2v.w, a3);
      a0 = fmaf(z.w, w3v.x, a0); a1 = fmaf(z.w, w3v.y, a1); a2 = fmaf(z.w, w3v.z, a2); a3 = fmaf(z.w, w3v.w, a3);
    }
  }
  float4 b3v = *(const float4*)&b3[tn*4];
  float4 w4v = *(const float4*)&w4[tn*4];
  float p = fmaxf(a0 + b3v.x, 0.f) * w4v.x
          + fmaxf(a1 + b3v.y, 0.f) * w4v.y
          + fmaxf(a2 + b3v.z, 0.f) * w4v.z
          + fmaxf(a3 + b3v.w, 0.f) * w4v.w;
  red[tid] = p;
  __syncthreads();
  if (tid < 16) {
    float s = 0.f;
    #pragma unroll
    for (int i = 0; i < 16; ++i) s += red[i*16 + tid];
    out[m0 + tid] = s + b4[0];
  }
}

extern "C" void kernel_launch(void* const* d_in, const int* in_sizes, int n_in,
                              void* d_out, int out_size, void* d_ws, size_t ws_size,
                              hipStream_t stream) {
  const float* x    = (const float*)d_in[0];
  const float* w1   = (const float*)d_in[1];
  const float* b1   = (const float*)d_in[2];
  const float* chw  = (const float*)d_in[3];
  const float* chb  = (const float*)d_in[4];
  const float* gnw  = (const float*)d_in[5];
  const float* gnb  = (const float*)d_in[6];
  const float* wq   = (const float*)d_in[7];
  const float* bq   = (const float*)d_in[8];
  const float* wk   = (const float*)d_in[9];
  const float* bk   = (const float*)d_in[10];
  const float* wv   = (const float*)d_in[11];
  const float* bv   = (const float*)d_in[12];
  const float* wp   = (const float*)d_in[13];
  const float* bp   = (const float*)d_in[14];
  const float* ch2w = (const float*)d_in[15];
  const float* ch2b = (const float*)d_in[16];
  const float* w2   = (const float*)d_in[17];
  const float* b2   = (const float*)d_in[18];
  const float* w3   = (const float*)d_in[19];
  const float* b3   = (const float*)d_in[20];
  const float* w4   = (const float*)d_in[21];
  const float* b4   = (const float*)d_in[22];
  (void)bk; (void)in_sizes; (void)n_in; (void)out_size; (void)ws_size;

  float* ws = (float*)d_ws;
  float* c2 = ws + WS_C2;
  float* z1 = ws + WS_Z1;
  float* out = (float*)d_out;

  hipLaunchKernelGGL(k0_precompute, dim3(34), dim3(256), 0, stream,
                     wq, bq, wk, bk, wv, bv, wp, bp, ws);
  hipLaunchKernelGGL(k1_sample, dim3(4096), dim3(384), 0, stream,
                     x, w1, b1, chw, chb, gnw, gnb, ch2w, ch2b, ws, c2);
  hipLaunchKernelGGL(k2_fc1, dim3(32, 12), dim3(256), 0, stream, c2, w2, b2, z1);
  hipLaunchKernelGGL(k3_fc23, dim3(256), dim3(256), 0, stream, z1, w3, b3, w4, b4, out);
}